// Round 3
// baseline (355.867 us; speedup 1.0000x reference)
//
#include <hip/hip_runtime.h>
#include <hip/hip_bf16.h>
#include <stdint.h>

// OFPenalty fused: per-batch Gram (49x49 from 2048x49) + two 9-step power
// iterations + penalty, all in ONE kernel (last-block-per-batch reduction).
//
// R3 structure (vs R2):
//  - Coalesced global->VGPR loads; bf16 hi/lo conversion done ONCE per
//    element; stored to a TRANSPOSED LDS tile T[n][k] (stride 72 bf16 = 9
//    bank-quads, odd -> conflict-free ds_read_b128 fragments).
//  - ATA = h^T h + E + E^T with E = h^T l  (l^T l dropped, rel ~2^-18):
//    2 MFMA chains instead of 3; E^T via one epilogue LDS transpose.
//  - Eigen fused: each batch's 4 gram blocks bump a device-scope counter
//    (threadfence release); the 4th runs the power iterations. Final sum
//    via a done-counter; last batch writes d_out. No spinning -> safe at
//    any occupancy/dispatch order. Counters zeroed by a 1 KB memset node.

#define BATCH 256
#define CDIM  2048
#define NDIM  49
#define QK    512                   // C rows per block (2048/4)
#define CHUNK 64                    // k rows per LDS stage
#define NCHUNK (QK / CHUNK)         // 8
#define KP    72                    // tile row stride (bf16): 144 B = 9 quads
#define TILE_ELEMS (64 * KP)        // one hi or lo tile (bf16 elems)
#define PSIZE (NDIM * NDIM)         // 2401
#define ESTR  65                    // Ebuf row stride (f32)
#define ASTR  53                    // eigen A row stride (f32)
#define CNT_OFF (1024 * PSIZE)      // float offset of counters in ws

typedef __bf16 bf16x8 __attribute__((ext_vector_type(8)));
typedef float  f32x16 __attribute__((ext_vector_type(16)));

__global__ __launch_bounds__(256, 4) void ofpenalty_fused(
    const float* __restrict__ x, const float* __restrict__ x0,
    float* __restrict__ partial, unsigned int* __restrict__ cnt,
    float* __restrict__ acc, unsigned int* __restrict__ done,
    float* __restrict__ out) {
  // 36864 B: tiles [buf][hi/lo][64][KP] while gram runs; Ebuf (16.6 KB) then
  // eigen A (10.4 KB) + xv overlay the same region, separated by barriers.
  __shared__ __align__(16) char smem[4 * TILE_ELEMS * 2];
  __shared__ int flag;
  __bf16* tile = (__bf16*)smem;
  float* Ebuf  = (float*)smem;
  float* Aeig  = (float*)smem;
  float* xv    = (float*)(smem + 10400);

  const int tid   = threadIdx.x;
  const int bidx  = blockIdx.x;       // 0..1023
  const int batch = bidx >> 2;
  const int q     = bidx & 3;
  const int w     = tid >> 6;         // wave 0..3
  const int lane  = tid & 63;
  const int ln    = lane & 31;
  const int hf    = lane >> 5;
  const int qm = w >> 1, qn = w & 1;
  const int rowA = qm * 32 + ln;
  const int rowB = qn * 32 + ln;

  const float* gbase = x + ((size_t)batch * CDIM + (size_t)q * QK) * NDIM;

  f32x16 c1, cE;
#pragma unroll
  for (int i = 0; i < 16; ++i) { c1[i] = 0.f; cE[i] = 0.f; }

  float L[2][8];  // in-flight chunk: wave w owns k-groups {w, w+4}

  // prologue: loads for chunk 0 (lane = spatial col n; coalesced per j)
  if (lane < NDIM) {
#pragma unroll
    for (int kk = 0; kk < 2; ++kk) {
      const int kg = w + kk * 4;
#pragma unroll
      for (int j = 0; j < 8; ++j)
        L[kk][j] = gbase[(size_t)(kg * 8 + j) * NDIM + lane];
    }
  }

  for (int ch = 0; ch < NCHUNK; ++ch) {
    const int buf = ch & 1;
    // convert + transposed store of chunk ch (consumes L)
    if (lane < NDIM) {
#pragma unroll
      for (int kk = 0; kk < 2; ++kk) {
        const int kg = w + kk * 4;
        bf16x8 h8, l8;
#pragma unroll
        for (int j = 0; j < 8; ++j) {
          float v = L[kk][j];
          __bf16 h = (__bf16)v;
          h8[j] = h;
          l8[j] = (__bf16)(v - (float)h);
        }
        *(bf16x8*)(tile + (buf * 2 + 0) * TILE_ELEMS + lane * KP + kg * 8) = h8;
        *(bf16x8*)(tile + (buf * 2 + 1) * TILE_ELEMS + lane * KP + kg * 8) = l8;
      }
    }
    __syncthreads();  // tiles[buf] visible; single barrier/iter is sufficient
                      // (cross-buffer WAR protected by the previous barrier)
    // issue loads for ch+1 AFTER the barrier so its vmcnt(0) drain
    // doesn't swallow them; they fly during the MFMA phase.
    if (ch + 1 < NCHUNK && lane < NDIM) {
      const float* cb = gbase + (size_t)((ch + 1) * CHUNK) * NDIM + lane;
#pragma unroll
      for (int kk = 0; kk < 2; ++kk) {
        const int kg = w + kk * 4;
#pragma unroll
        for (int j = 0; j < 8; ++j)
          L[kk][j] = cb[(size_t)(kg * 8 + j) * NDIM];
      }
    }
    const __bf16* th = tile + (buf * 2 + 0) * TILE_ELEMS;
    const __bf16* tl = tile + (buf * 2 + 1) * TILE_ELEMS;
#pragma unroll
    for (int s = 0; s < 4; ++s) {
      const int g = s * 2 + hf;          // k = s*16 + hf*8 + j
      bf16x8 ah = *(const bf16x8*)(th + rowA * KP + g * 8);
      bf16x8 bh = *(const bf16x8*)(th + rowB * KP + g * 8);
      bf16x8 bl = *(const bf16x8*)(tl + rowB * KP + g * 8);
      c1 = __builtin_amdgcn_mfma_f32_32x32x16_bf16(ah, bh, c1, 0, 0, 0);
      cE = __builtin_amdgcn_mfma_f32_32x32x16_bf16(ah, bl, cE, 0, 0, 0);
    }
  }

  // Epilogue: ATA = c1 + E + E^T.  E^T via LDS exchange (tiles are dead).
  __syncthreads();
#pragma unroll
  for (int r = 0; r < 16; ++r) {
    const int mm = qm * 32 + (r & 3) + 8 * (r >> 2) + 4 * hf;
    Ebuf[mm * ESTR + (qn * 32 + ln)] = cE[r];
  }
  __syncthreads();
  float* outp = partial + (size_t)bidx * PSIZE;
  const int n = qn * 32 + ln;
#pragma unroll
  for (int r = 0; r < 16; ++r) {
    const int mm = qm * 32 + (r & 3) + 8 * (r >> 2) + 4 * hf;
    if (mm < NDIM && n < NDIM)
      outp[mm * NDIM + n] = c1[r] + cE[r] + Ebuf[n * ESTR + mm];
  }

  // release our tile, bump the batch counter; 4th arriver runs eigen
  __threadfence();
  __syncthreads();
  if (tid == 0) {
    unsigned int old = atomicAdd(&cnt[batch], 1u);
    flag = (old == 3u) ? 1 : 0;
  }
  __syncthreads();
  if (!flag) return;
  __threadfence();  // acquire side: other blocks' tiles now visible

  // ---- eigen phase (validated R2 arithmetic, A sourced from the 4 tiles) ----
  const float* p0 = partial + (size_t)(batch * 4) * PSIZE;
  for (int idx = tid; idx < PSIZE; idx += 256) {
    int r = idx / NDIM, c = idx - r * NDIM;
    float v = 0.f;
#pragma unroll
    for (int qq = 0; qq < 4; ++qq) v += p0[qq * PSIZE + idx];
    Aeig[r * ASTR + c] = v;
  }
  if (tid < NDIM) xv[tid] = x0[batch * NDIM + tid];
  __syncthreads();

  const int t = tid;
  auto rayleigh_power = [&](float shift) -> float {
    for (int it = 0; it < 9; ++it) {
      float y = 0.f;
      if (t < NDIM) {
        const float* Ar = &Aeig[t * ASTR];
#pragma unroll 7
        for (int k = 0; k < NDIM; ++k) y = fmaf(Ar[k], xv[k], y);
        y -= shift * xv[t];
      }
      float s = y * y;
#pragma unroll
      for (int o = 32; o; o >>= 1) s += __shfl_xor(s, o, 64);
      float nrm = fmaxf(sqrtf(s), 1e-12f);  // F.normalize eps
      __syncthreads();
      if (t < NDIM) xv[t] = y / nrm;
      __syncthreads();
    }
    float yy = 0.f;
    if (t < NDIM) {
      const float* Ar = &Aeig[t * ASTR];
#pragma unroll 7
      for (int k = 0; k < NDIM; ++k) yy = fmaf(Ar[k], xv[k], yy);
      yy -= shift * xv[t];
    }
    float num = (t < NDIM) ? yy * xv[t] : 0.f;
    float den = (t < NDIM) ? xv[t] * xv[t] : 0.f;
#pragma unroll
    for (int o = 32; o; o >>= 1) {
      num += __shfl_xor(num, o, 64);
      den += __shfl_xor(den, o, 64);
    }
    return num / den;
  };

  float largest = rayleigh_power(0.f);
  float tmp = rayleigh_power(largest);  // warm start: xv == x1 already
  float smallest = tmp + largest;

  if (t == 0) {
    float r = largest / smallest - 1.f;
    atomicAdd(acc, r * r * (1.0f / (float)BATCH));  // BETA = 1
    __threadfence();
    unsigned int od = atomicAdd(done, 1u);
    if (od == BATCH - 1) {
      __threadfence();
      out[0] = atomicAdd(acc, 0.0f);  // old value == full sum
    }
  }
}

extern "C" void kernel_launch(void* const* d_in, const int* in_sizes, int n_in,
                              void* d_out, int out_size, void* d_ws,
                              size_t ws_size, hipStream_t stream) {
  const float* x  = (const float*)d_in[0];   // [256,2048,7,7] fp32
  const float* x0 = (const float*)d_in[1];   // [256,49,1] fp32 (pre-normalized)
  float* out = (float*)d_out;                // scalar fp32
  float* partial = (float*)d_ws;             // 1024 * 2401 f32 = 9.83 MB
  unsigned int* cnt  = (unsigned int*)(partial + CNT_OFF);  // 256 u32
  float*        acc  = (float*)(cnt + 256);                 // 1 f32
  unsigned int* done = (unsigned int*)(cnt + 257);          // 1 u32

  hipMemsetAsync((void*)cnt, 0, 258 * sizeof(unsigned int), stream);
  ofpenalty_fused<<<1024, 256, 0, stream>>>(x, x0, partial, cnt, acc, done, out);
}

// Round 4
// 179.295 us; speedup vs baseline: 1.9848x; 1.9848x over previous
//
#include <hip/hip_runtime.h>
#include <hip/hip_bf16.h>
#include <stdint.h>

// OFPenalty: per-batch Gram (49x49 from 2048x49) -> two 9-step power
// iterations -> penalty scalar. Memory-bound on reading x (102.8 MB; floor
// ~16.3 us at 6.3 TB/s).
//
// R4 (revert R3 fusion; keep R2 skeleton, fix its conversion bottleneck):
//  - global_load_lds fp32 staging, double-buffered raw (validated R1/R2).
//  - NEW: cooperative convert-once pass per chunk: LDS raw fp32 ->
//    hi/lo bf16 fragment cells [g][n][8k] (16B cells, conflict-free b128).
//    Kills the per-wave-redundant cvt + 16x scalar ds_read per MFMA step.
//  - 2 MFMA chains (ATA = H + E + E^T, E = h^T l; l^T l dropped ~2^-18) with
//    Ebuf-transpose epilogue — exact math validated in R3 (absmax 0.0).
//  - Separate eigen kernel: R2 version verbatim (validated).

#define BATCH 256
#define CDIM  2048
#define NDIM  49
#define QK    512                    // C rows per block (2048/4)
#define CHUNK 64                     // k rows per LDS stage
#define NCHUNK (QK / CHUNK)          // 8
#define CH_FLOATS (CHUNK * NDIM)     // 3136
#define CH_SLOTS  (CH_FLOATS / 4)    // 784 16B DMA slots
#define TN    56                     // tile n capacity (>=49; rows clamp)
#define NSLICE (8 * TN)              // 448 (g,n) cells per chunk
#define TILE_BYTES (8 * TN * 8 * 2)  // 7168 per hi/lo tile
#define RAW_BYTES (2 * CH_FLOATS * 4)// 25088 (dbuf)
#define PSIZE (NDIM * NDIM)          // 2401
#define ESTR  65                     // Ebuf row stride (f32)
#define ASTR  53                     // eigen A row stride (f32)

typedef __bf16 bf16x8 __attribute__((ext_vector_type(8)));
typedef float  f32x16 __attribute__((ext_vector_type(16)));

__device__ inline void async_load16(const float* g, float* l) {
  __builtin_amdgcn_global_load_lds(
      (const __attribute__((address_space(1))) void*)g,
      (__attribute__((address_space(3))) void*)l,
      16 /*bytes*/, 0 /*offset*/, 0 /*aux*/);
}

__global__ __launch_bounds__(256, 4) void gram_kernel(
    const float* __restrict__ x, float* __restrict__ partial,
    float* __restrict__ out) {
  // 39424 B -> 4 blocks/CU. Layout: raw dbuf | tileH | tileL.
  // Ebuf (64x65 f32 = 16640 B) overlays raw in the epilogue (raw is dead).
  __shared__ __align__(16) char smem[RAW_BYTES + 2 * TILE_BYTES];
  float*  raw0 = (float*)smem;
  float*  raw1 = (float*)(smem + CH_FLOATS * 4);
  __bf16* tH   = (__bf16*)(smem + RAW_BYTES);
  __bf16* tL   = (__bf16*)(smem + RAW_BYTES + TILE_BYTES);
  float*  Ebuf = (float*)smem;

  const int tid   = threadIdx.x;
  const int bidx  = blockIdx.x;       // 0..1023
  const int batch = bidx >> 2;
  const int q     = bidx & 3;
  const int w     = tid >> 6;         // wave 0..3
  const int lane  = tid & 63;
  const int ln    = lane & 31;
  const int hf    = lane >> 5;
  const int qm = w >> 1, qn = w & 1;
  const int rowA = min(qm * 32 + ln, TN - 1);  // clamped: garbage rows only
  const int rowB = min(qn * 32 + ln, TN - 1);  // feed discarded outputs
  const int nOut = qn * 32 + ln;               // true output column

  if (bidx == 0 && tid == 0) out[0] = 0.f;  // replaces memset dispatch

  const float* gbase = x + ((size_t)batch * CDIM + (size_t)q * QK) * NDIM;

  f32x16 c1, cE;
#pragma unroll
  for (int i = 0; i < 16; ++i) { c1[i] = 0.f; cE[i] = 0.f; }

  // convert-pass slice assignment (fixed per thread)
  const int s1ok = (tid < NSLICE - 256);       // 192 threads take 2nd slice
  const int n0 = tid % TN,         g0 = tid / TN;
  const int n1 = (256 + tid) % TN, g1 = (256 + tid) / TN;

  // prologue DMA: chunk 0 -> raw0
#pragma unroll
  for (int i = 0; i < 4; ++i) {
    int slot = i * 256 + tid;
    if (slot < CH_SLOTS) async_load16(gbase + slot * 4, raw0 + slot * 4);
  }

  for (int ch = 0; ch < NCHUNK; ++ch) {
    float* cur = (ch & 1) ? raw1 : raw0;
    float* nxt = (ch & 1) ? raw0 : raw1;
    __syncthreads();  // barrier A: DMA(ch) drained+visible; tiles consumed

    if (ch + 1 < NCHUNK) {  // DMA chunk ch+1; flies across convert phase
      const float* gch = gbase + (size_t)(ch + 1) * CH_FLOATS;
#pragma unroll
      for (int i = 0; i < 4; ++i) {
        int slot = i * 256 + tid;
        if (slot < CH_SLOTS) async_load16(gch + slot * 4, nxt + slot * 4);
      }
    }

    // convert-once: raw fp32 -> hi/lo bf16 fragment cells [g][n][8]
    if (n0 < NDIM) {
      const float* rp = cur + g0 * 8 * NDIM + n0;
      bf16x8 h8, l8;
#pragma unroll
      for (int j = 0; j < 8; ++j) {
        float v = rp[j * NDIM];
        __bf16 h = (__bf16)v;
        h8[j] = h;
        l8[j] = (__bf16)(v - (float)h);
      }
      *(bf16x8*)(tH + (g0 * TN + n0) * 8) = h8;
      *(bf16x8*)(tL + (g0 * TN + n0) * 8) = l8;
    }
    if (s1ok && n1 < NDIM) {
      const float* rp = cur + g1 * 8 * NDIM + n1;
      bf16x8 h8, l8;
#pragma unroll
      for (int j = 0; j < 8; ++j) {
        float v = rp[j * NDIM];
        __bf16 h = (__bf16)v;
        h8[j] = h;
        l8[j] = (__bf16)(v - (float)h);
      }
      *(bf16x8*)(tH + (g1 * TN + n1) * 8) = h8;
      *(bf16x8*)(tL + (g1 * TN + n1) * 8) = l8;
    }
    __syncthreads();  // barrier B: tiles ready

#pragma unroll
    for (int g2 = 0; g2 < 4; ++g2) {
      const int g = g2 * 2 + hf;     // k = g2*16 + hf*8 + j
      bf16x8 ah = *(const bf16x8*)(tH + (g * TN + rowA) * 8);
      bf16x8 bh;
      if (qm == qn) bh = ah;         // diagonal quadrant: A row == B row
      else          bh = *(const bf16x8*)(tH + (g * TN + rowB) * 8);
      bf16x8 bl = *(const bf16x8*)(tL + (g * TN + rowB) * 8);
      c1 = __builtin_amdgcn_mfma_f32_32x32x16_bf16(ah, bh, c1, 0, 0, 0);
      cE = __builtin_amdgcn_mfma_f32_32x32x16_bf16(ah, bl, cE, 0, 0, 0);
    }
  }

  // Epilogue: ATA = c1 + E + E^T; E^T via LDS transpose (raw is dead).
  __syncthreads();
#pragma unroll
  for (int r = 0; r < 16; ++r) {
    const int mm = qm * 32 + (r & 3) + 8 * (r >> 2) + 4 * hf;
    Ebuf[mm * ESTR + nOut] = cE[r];
  }
  __syncthreads();
  float* outp = partial + (size_t)bidx * PSIZE;
#pragma unroll
  for (int r = 0; r < 16; ++r) {
    const int mm = qm * 32 + (r & 3) + 8 * (r >> 2) + 4 * hf;
    if (mm < NDIM && nOut < NDIM)
      outp[mm * NDIM + nOut] = c1[r] + cE[r] + Ebuf[nOut * ESTR + mm];
  }
}

__global__ __launch_bounds__(64) void eigen_kernel(
    const float* __restrict__ partial, const float* __restrict__ x0,
    float* __restrict__ out) {
  __shared__ float A[NDIM * ASTR];
  __shared__ float xv[64];

  const int b = blockIdx.x;
  const int t = threadIdx.x;  // 0..63
  const float* p0 = partial + (size_t)(4 * b) * PSIZE;

  for (int idx = t; idx < NDIM * NDIM; idx += 64) {
    int r = idx / NDIM;
    int c = idx - r * NDIM;
    float v = 0.f;
#pragma unroll
    for (int qq = 0; qq < 4; ++qq) v += p0[qq * PSIZE + idx];
    A[r * ASTR + c] = v;
  }
  if (t < NDIM) xv[t] = x0[b * NDIM + t];
  __syncthreads();

  auto rayleigh_power = [&](float shift) -> float {
    for (int it = 0; it < 9; ++it) {
      float y = 0.f;
      if (t < NDIM) {
        const float* Ar = &A[t * ASTR];
#pragma unroll 7
        for (int k = 0; k < NDIM; ++k) y = fmaf(Ar[k], xv[k], y);
        y -= shift * xv[t];
      }
      float s = y * y;
#pragma unroll
      for (int o = 32; o; o >>= 1) s += __shfl_xor(s, o, 64);
      float nrm = fmaxf(sqrtf(s), 1e-12f);  // F.normalize eps
      __syncthreads();
      if (t < NDIM) xv[t] = y / nrm;
      __syncthreads();
    }
    float yy = 0.f;
    if (t < NDIM) {
      const float* Ar = &A[t * ASTR];
#pragma unroll 7
      for (int k = 0; k < NDIM; ++k) yy = fmaf(Ar[k], xv[k], yy);
      yy -= shift * xv[t];
    }
    float num = (t < NDIM) ? yy * xv[t] : 0.f;
    float den = (t < NDIM) ? xv[t] * xv[t] : 0.f;
#pragma unroll
    for (int o = 32; o; o >>= 1) {
      num += __shfl_xor(num, o, 64);
      den += __shfl_xor(den, o, 64);
    }
    return num / den;
  };

  float largest = rayleigh_power(0.f);
  float tmp = rayleigh_power(largest);  // warm start: xv == x1 already
  float smallest = tmp + largest;

  if (t == 0) {
    float r = largest / smallest - 1.f;
    atomicAdd(out, r * r * (1.0f / (float)BATCH));  // BETA = 1
  }
}

extern "C" void kernel_launch(void* const* d_in, const int* in_sizes, int n_in,
                              void* d_out, int out_size, void* d_ws,
                              size_t ws_size, hipStream_t stream) {
  const float* x  = (const float*)d_in[0];   // [256,2048,7,7] fp32
  const float* x0 = (const float*)d_in[1];   // [256,49,1] fp32 (pre-normalized)
  float* out = (float*)d_out;                // scalar fp32
  float* partial = (float*)d_ws;             // 1024 * 2401 f32 = 9.83 MB

  gram_kernel<<<1024, 256, 0, stream>>>(x, partial, out);
  eigen_kernel<<<BATCH, 64, 0, stream>>>(partial, x0, out);
}